// Round 3
// baseline (819.911 us; speedup 1.0000x reference)
//
#include <hip/hip_runtime.h>

// Problem constants (fixed by setup_inputs): im0 [B,C,H,W] fp32,
// flow [B,H,W,2] fp32, out [B,C,H,W] fp32.
constexpr int B_ = 4;
constexpr int C_ = 3;
constexpr int H_ = 1024;
constexpr int W_ = 1920;
constexpr int HW_ = H_ * W_;

// Tile: block of 256 threads owns TW x TH pixels; splats accumulate in an
// LDS tile extended by halo R, one channel at a time. 40 KB LDS -> exactly
// 4 blocks/CU (16 waves/CU) vs round-2's 61 KB (2 blocks/CU).
constexpr int TW = 128;
constexpr int TH = 32;
constexpr int R  = 16;
constexpr int EW = TW + 2 * R;      // 160
constexpr int EH = TH + 2 * R;      // 64
constexpr int ECELLS = EW * EH;     // 10240 cells -> 40960 B

static_assert(W_ % TW == 0 && H_ % TH == 0, "exact tiling assumed");

template <int MODE>
__device__ __forceinline__ void splat_one(float* __restrict__ tile,
                                          float* __restrict__ outc,
                                          int ex0, int ey0,
                                          int x, int y, float fx, float fy,
                                          float s) {
    const float px = (float)x + fx;
    const float py = (float)y + fy;
    if (MODE == 1) {
        const int xi = (int)rintf(px);
        const int yi = (int)rintf(py);
        const int exi = xi - ex0, eyi = yi - ey0;
        if ((unsigned)exi < (unsigned)EW && (unsigned)eyi < (unsigned)EH) {
            atomicAdd(&tile[eyi * EW + exi], s);
        } else if ((unsigned)xi < (unsigned)W_ && (unsigned)yi < (unsigned)H_) {
            unsafeAtomicAdd(outc + yi * W_ + xi, s);
        }
    } else {
        const float xf = floorf(px), yf = floorf(py);
        const int x0 = (int)xf, y0 = (int)yf;
        const float wx1 = px - xf, wy1 = py - yf;
        const float wx0 = 1.0f - wx1, wy0 = 1.0f - wy1;
        const int cx[4] = {x0, x0 + 1, x0, x0 + 1};
        const int cy[4] = {y0, y0, y0 + 1, y0 + 1};
        const float cw[4] = {wx0 * wy0, wx1 * wy0, wx0 * wy1, wx1 * wy1};
#pragma unroll
        for (int k = 0; k < 4; ++k) {
            const int exi = cx[k] - ex0;
            const int eyi = cy[k] - ey0;
            const float v = s * cw[k];
            if ((unsigned)exi < (unsigned)EW && (unsigned)eyi < (unsigned)EH) {
                atomicAdd(&tile[eyi * EW + exi], v);       // ds_add_f32
            } else if ((unsigned)cx[k] < (unsigned)W_ &&
                       (unsigned)cy[k] < (unsigned)H_) {
                unsafeAtomicAdd(outc + cy[k] * W_ + cx[k], v);  // ~0.3% of corners
            }
        }
    }
}

template <int MODE>
__device__ __forceinline__ void warp_body(const float* __restrict__ im0,
                                          const float* __restrict__ flowf,
                                          float* __restrict__ out,
                                          float* __restrict__ tile) {
    const int tx0 = blockIdx.x * TW;
    const int ty0 = blockIdx.y * TH;
    const int b   = blockIdx.z;
    const int ex0 = tx0 - R;
    const int ey0 = ty0 - R;

    float4* const tile4 = (float4*)tile;

    for (int c = 0; c < C_; ++c) {
        // --- zero LDS tile (float4 stores) ---
        for (int v = threadIdx.x; v < ECELLS / 4; v += 256)
            tile4[v] = make_float4(0.f, 0.f, 0.f, 0.f);
        __syncthreads();

        const float* im0c = im0 + ((size_t)(b * C_ + c)) * HW_;
        float* outc = out + ((size_t)(b * C_ + c)) * HW_;

        // --- splat: 2 pixels per thread-iteration ---
        for (int q = threadIdx.x; q < (TW * TH) / 2; q += 256) {
            const int lp = q & 63;          // pair index in row (TW/2 == 64)
            const int ly = q >> 6;
            const int x = tx0 + lp * 2;
            const int y = ty0 + ly;
            const float4 f = *(const float4*)&flowf[((size_t)(b * H_ + y) * W_ + x) * 2];
            const float2 s = *(const float2*)&im0c[y * W_ + x];
            splat_one<MODE>(tile, outc, ex0, ey0, x,     y, f.x, f.y, s.x);
            splat_one<MODE>(tile, outc, ex0, ey0, x + 1, y, f.z, f.w, s.y);
        }
        __syncthreads();

        // --- flush ext tile to global (float4 reads, skip zeros) ---
        for (int v = threadIdx.x; v < ECELLS / 4; v += 256) {
            const float4 val = tile4[v];
            if (val.x == 0.f && val.y == 0.f && val.z == 0.f && val.w == 0.f)
                continue;
            const int eyi = v / (EW / 4);               // 40 float4 per row
            const int exi = (v - eyi * (EW / 4)) * 4;
            const int gy = ey0 + eyi;
            const int gx = ex0 + exi;
            if ((unsigned)gy < (unsigned)H_) {
                float* row = outc + gy * W_;
                if (val.x != 0.f && (unsigned)(gx + 0) < (unsigned)W_)
                    unsafeAtomicAdd(row + gx + 0, val.x);
                if (val.y != 0.f && (unsigned)(gx + 1) < (unsigned)W_)
                    unsafeAtomicAdd(row + gx + 1, val.y);
                if (val.z != 0.f && (unsigned)(gx + 2) < (unsigned)W_)
                    unsafeAtomicAdd(row + gx + 2, val.z);
                if (val.w != 0.f && (unsigned)(gx + 3) < (unsigned)W_)
                    unsafeAtomicAdd(row + gx + 3, val.w);
            }
        }
        __syncthreads();   // before re-zeroing for the next channel
    }
}

__global__ __launch_bounds__(256, 4) void forward_warp_tiled(
    const float* __restrict__ im0,
    const float* __restrict__ flowf,
    const int* __restrict__ mode_p,
    float* __restrict__ out) {
    __shared__ float tile[ECELLS];
    if (*mode_p == 1)
        warp_body<1>(im0, flowf, out, tile);
    else
        warp_body<0>(im0, flowf, out, tile);
}

extern "C" void kernel_launch(void* const* d_in, const int* in_sizes, int n_in,
                              void* d_out, int out_size, void* d_ws, size_t ws_size,
                              hipStream_t stream) {
    const float* im0   = (const float*)d_in[0];
    const float* flowf = (const float*)d_in[1];
    // d_in[2] = flowback (unused by the forward splat)
    const int*   mode  = (const int*)d_in[3];
    float* out = (float*)d_out;

    // Output accumulates via atomics -> zero it every call (harness poisons
    // d_out with 0xAA before each timed launch).
    (void)hipMemsetAsync(d_out, 0, (size_t)out_size * sizeof(float), stream);

    dim3 grid(W_ / TW, H_ / TH, B_);
    forward_warp_tiled<<<grid, dim3(256), 0, stream>>>(im0, flowf, mode, out);
}